// Round 10
// baseline (289.683 us; speedup 1.0000x reference)
//
#include <hip/hip_runtime.h>
#include <stdint.h>

typedef __attribute__((ext_vector_type(8))) short bf16x8;
typedef __attribute__((ext_vector_type(4))) float f32x4;
typedef __attribute__((ext_vector_type(4))) unsigned short u16x4;

#define NB 32
#define HH 128
#define WW 128
#define CI 128
#define CO 128
#define HO 126
#define WO 126
#define TH 8            // output tile h (4-wave, 256-thread blocks)
#define TW 16
#define PHh 10          // patch h = TH + 2
#define PWw 18          // patch w = TW + 2
#define NROW (PHh * PWw)   // 180 patch rows
#define RSTR 72            // shorts per LDS row (144 B) — affine, immediates only
#define RSTRB 144

__device__ __forceinline__ unsigned short f2bf(float f) {
  union { float f; unsigned u; } x; x.f = f;
  unsigned u = x.u;
  u += 0x7FFFu + ((u >> 16) & 1u);   // RNE round to bf16
  return (unsigned short)(u >> 16);
}

// cvt_pk_bf16_f32: RNE, packs 2 f32 -> 2 bf16 in one VALU op (no builtin on gfx950)
__device__ __forceinline__ unsigned cvtpk_bf16(float a, float b) {
  unsigned r;
  asm("v_cvt_pk_bf16_f32 %0, %1, %2" : "=v"(r) : "v"(a), "v"(b));
  return r;  // low16 = bf16(a), high16 = bf16(b)
}

// prep: [b,p][ci][co] f32 -> fragment-blocked bf16, slice-major [b][ch][p][kc]:
//   slice = (ch*9+p)*2+kc (4096 shorts each); within: f*512 + lane*8 + e
//   holds kin[b,p][ci = ch*64+kc*32+(lane>>4)*8+e][co = (f>>2)*64+(f&3)*16+(lane&15)]
__global__ void prep_kt(const float* __restrict__ kin, unsigned short* __restrict__ ktr) {
  __shared__ unsigned short t[CI * CO];  // 32 KB
  int bp = blockIdx.x;  // b*9+p, 0..287
  int b = bp / 9, p = bp % 9;
  const float* src = kin + (size_t)bp * (CI * CO);
  unsigned short* dstb = ktr + (size_t)b * (9 * CI * CO);
  for (int i = threadIdx.x; i < CI * CO / 4; i += blockDim.x) {
    f32x4 v = *(const f32x4*)(src + i * 4);
    u16x4 o;
    o.x = f2bf(v.x); o.y = f2bf(v.y); o.z = f2bf(v.z); o.w = f2bf(v.w);
    *(u16x4*)&t[i * 4] = o;
  }
  __syncthreads();
  for (int j = threadIdx.x; j < 2048; j += blockDim.x) {  // j = (sl*8+f)*64+lane
    int lane = j & 63, f = (j >> 6) & 7, sl = j >> 9;     // sl = ch*2+kc
    int ch = sl >> 1, kc = sl & 1;
    int co = (f >> 2) * 64 + (f & 3) * 16 + (lane & 15);
    int ci0 = ch * 64 + kc * 32 + (lane >> 4) * 8;
    bf16x8 v;
#pragma unroll
    for (int e = 0; e < 8; ++e) v[e] = t[(ci0 + e) * CO + co];
    int slice = (ch * 9 + p) * 2 + kc;
    *(bf16x8*)&dstb[(size_t)slice * 4096 + f * 512 + lane * 8] = v;
  }
}

// naive fallback (only if ws_size too small — not expected on this harness)
__global__ void conv_naive(const float* __restrict__ X, const float* __restrict__ Kf,
                           float* __restrict__ out) {
  int idx = blockIdx.x * blockDim.x + threadIdx.x;           // over B*HO*WO*CO
  if (idx >= NB * HO * WO * CO) return;
  int co = idx & 127, t = idx >> 7;
  int wp = t % WO; t /= WO;
  int hp = t % HO; int b = t / HO;
  const float* xb = X + (size_t)b * HH * WW * CI;
  const float* kb = Kf + (size_t)b * 9 * CI * CO;
  float s = 0.f;
  for (int p = 0; p < 9; ++p) {
    int kh = p / 3, kw = p % 3;
    const float* xr = xb + ((size_t)(hp + kh) * WW + (wp + kw)) * CI;
    const float* kr = kb + (size_t)p * CI * CO + co;
    for (int ci = 0; ci < CI; ++ci) s += xr[ci] * kr[(size_t)ci * CO];
  }
  out[idx] = s;
}

// 256-thread blocks, 3 blocks/CU (~170 regs/thd budget). BOTH operand streams
// double-buffered: af (LDS A-frags) AND Hf (global B-frags). Cluster s issues
// the s+1 loads BEFORE its MFMAs, so the B consume-wait is a counted
// vmcnt(4) with a full MFMA-cluster of slack — removing the per-cluster
// vmcnt(0)-style drain (~200-900 cyc VMEM latency fully exposed in R0-R9,
// the pinned-~30%-MfmaUtil cause; cf. T4/m218 counted-vs-drain +38-73%).
__global__ __launch_bounds__(256, 3) void conv_main(
    const float* __restrict__ X, const unsigned short* __restrict__ Kt,
    float* __restrict__ out) {
  // One Cin-half of the 10x18 patch; rows padded to 144 B: every compute LDS
  // address is base + compile-time immediate (anti-spill invariant, R3/R4).
  __shared__ unsigned short lds_a[NROW * RSTR];  // 25920 B -> 3 blocks/CU

  const int tid = threadIdx.x;
  const int lane = tid & 63;
  const int wid = tid >> 6;            // 4 waves, 2 (h) x 2 (co)
  const int wr = wid >> 1, wc = wid & 1;

  // XCD-clustered block swizzle: 4 whole batches per XCD (L2-resident B).
  const int l = blockIdx.x;            // 0..4095
  const int xcd = l & 7, j = l >> 3;   // j: 0..511
  const int b = xcd * 4 + (j >> 7);    // 4 batches per XCD
  const int t = j & 127;               // tile within batch (16h x 8w)
  const int ht = t >> 3, wt = t & 7;
  const int h0 = ht * TH, w0 = wt * TW;
  const int ks = lane >> 4, lr = lane & 15;

  const float* xb = X + (size_t)b * HH * WW * CI;

  // ---- stage: slot s = tid + k*256; row = (tid>>4) + 16k; ci4 = tid&15 ----
  // affine: dst byte = row*144 + ci4*8, advances 2304 B per k (ds imm).
  const int ci4 = tid & 15;
  const int row0 = tid >> 4;                  // 0..15 (all h=0, w=row0)
  char* const dst0 = (char*)lds_a + row0 * RSTRB + ci4 * 8;

  auto stageA = [&](int ch) {
    int h = 0, w = row0;
    const float* srcb = xb + ch * 64 + ci4 * 4;
#pragma unroll
    for (int k = 0; k < 12; ++k) {            // 11 full rounds + 4-row tail
      if (k < 11 || tid < 64) {
        int gh = h0 + h, gw = w0 + w;
        bool ok = (gh | gw) < HH;             // gh<128 && gw<128 (both <256)
        const float* src = srcb + ((size_t)(((gh & 127) << 7) + (gw & 127)) << 7);
        f32x4 v = *(const f32x4*)src;
        uint2 o;
        o.x = ok ? cvtpk_bf16(v.x, v.y) : 0u;
        o.y = ok ? cvtpk_bf16(v.z, v.w) : 0u;
        *(uint2*)(dst0 + k * (16 * RSTRB)) = o;  // folds into ds imm
      }
      w += 16;                                // advance 16 rows
      if (w >= PWw) { w -= PWw; h += 1; }
    }
  };

  // ---- compute: af byte = aoff + ((m+kh)*18 + kw)*144 + kc*64 (imm) ----
  const int aoff = ((wr * 4) * PWw + lr) * RSTRB + ks * 16;
  const char* ldsb = (const char*)lds_a;

  f32x4 zero = {0.f, 0.f, 0.f, 0.f};
  f32x4 acc[4][4];
#pragma unroll
  for (int m = 0; m < 4; ++m)
#pragma unroll
    for (int n = 0; n < 4; ++n) acc[m][n] = zero;

  // B slices: slice = ch*18 + s; 4 contiguous 1KB bursts per wave (L2-res).
  const unsigned short* ktw = Kt + (size_t)b * 9 * CI * CO + (wc * 4) * 512 + lane * 8;
  bf16x8 HfA[4], HfB[4];
  auto loadB = [&](bf16x8 (&dst)[4], int slice) {
#pragma unroll
    for (int n = 0; n < 4; ++n)
      dst[n] = *(const bf16x8*)&ktw[(size_t)slice * 4096 + n * 512];
  };

  bf16x8 afA[4], afB[4];
  auto issueAf = [&](bf16x8 (&dst)[4], int s) {   // s compile-time via unroll
    const int kh = s / 6, jj = s % 6;
    const int kw = jj >> 1, kc = jj & 1;
#pragma unroll
    for (int m = 0; m < 4; ++m)
      dst[m] = *(const bf16x8*)(ldsb + aoff +
                                ((m + kh) * PWw * RSTRB + kw * RSTRB + kc * 64));
  };
  auto mma = [&](bf16x8 (&a)[4], bf16x8 (&h)[4]) {
    __builtin_amdgcn_s_setprio(1);
#pragma unroll
    for (int m = 0; m < 4; ++m)
#pragma unroll
      for (int n = 0; n < 4; ++n)
        acc[m][n] = __builtin_amdgcn_mfma_f32_16x16x32_bf16(a[m], h[n], acc[m][n], 0, 0, 0);
    __builtin_amdgcn_s_setprio(0);
  };

#pragma unroll 1
  for (int ch = 0; ch < 2; ++ch) {
    if (ch) __syncthreads();           // all waves done reading previous half
    if (ch == 0) loadB(HfA, 0);        // ch1's slice 18 prefetched at ch0 s=17
    stageA(ch);
    __syncthreads();                   // lds_a ready (drains stage + B loads)
    issueAf(afA, 0);                   // prime the A-side pipeline
#pragma unroll
    for (int u = 0; u < 9; ++u) {      // 18 clusters as 9 ping-pong pairs
      {
        const int s = 2 * u;           // even: consume afA/HfA
        loadB(HfB, ch * 18 + s + 1);   // s+1 <= 17 always here
        issueAf(afB, s + 1);
        mma(afA, HfA);                 // waits: vmcnt(4) (HfB in flight)
      }
      {
        const int s = 2 * u + 1;       // odd: consume afB/HfB
        if (s < 17) {
          loadB(HfA, ch * 18 + s + 1);
          issueAf(afA, s + 1);
        } else if (ch == 0) {
          loadB(HfA, 18);              // cross-barrier prefetch of ch1 slice 0
        }
        mma(afB, HfB);
      }
    }
  }

  // ---- epilogue: C/D map col=lane&15 (cout), row=(lane>>4)*4+reg (pw) ----
  float* ob = out + (size_t)b * HO * WO * CO;
#pragma unroll
  for (int m = 0; m < 4; ++m) {
    int hp = h0 + wr * 4 + m;
    if (hp >= HO) continue;
#pragma unroll
    for (int r = 0; r < 4; ++r) {
      int wp = w0 + ks * 4 + r;
      if (wp >= WO) continue;
#pragma unroll
      for (int n = 0; n < 4; ++n) {
        int co = wc * 64 + n * 16 + lr;
        ob[((size_t)hp * WO + wp) * CO + co] = acc[m][n][r];
      }
    }
  }
}

extern "C" void kernel_launch(void* const* d_in, const int* in_sizes, int n_in,
                              void* d_out, int out_size, void* d_ws, size_t ws_size,
                              hipStream_t stream) {
  const float* X = (const float*)d_in[0];
  const float* Kf = (const float*)d_in[1];
  float* out = (float*)d_out;
  size_t need = (size_t)NB * 9 * CI * CO * sizeof(unsigned short);  // 9.4 MB
  if (d_ws != nullptr && ws_size >= need) {
    unsigned short* ktr = (unsigned short*)d_ws;
    prep_kt<<<dim3(NB * 9), 256, 0, stream>>>(Kf, ktr);
    conv_main<<<dim3(4096), 256, 0, stream>>>(X, ktr, out);
  } else {
    int total = NB * HO * WO * CO;
    conv_naive<<<(total + 255) / 256, 256, 0, stream>>>(X, Kf, out);
  }
}

// Round 11
// 187.414 us; speedup vs baseline: 1.5457x; 1.5457x over previous
//
#include <hip/hip_runtime.h>
#include <stdint.h>

typedef __attribute__((ext_vector_type(8))) short bf16x8;
typedef __attribute__((ext_vector_type(4))) float f32x4;
typedef __attribute__((ext_vector_type(4))) unsigned short u16x4;
typedef __attribute__((ext_vector_type(4))) unsigned int u32x4;

#define NB 32
#define HH 128
#define WW 128
#define CI 128
#define CO 128
#define HO 126
#define WO 126
#define TH 16
#define TW 16
#define PHh 18
#define PWw 18
#define NROW (PHh * PWw)   // 324 patch rows
#define RSTR 72            // shorts per LDS row (144 B): affine immediates only
#define RSTRB 144

__device__ __forceinline__ unsigned short f2bf(float f) {
  union { float f; unsigned u; } x; x.f = f;
  unsigned u = x.u;
  u += 0x7FFFu + ((u >> 16) & 1u);   // RNE round to bf16
  return (unsigned short)(u >> 16);
}

// cvt_pk_bf16_f32: RNE, packs 2 f32 -> 2 bf16 in one VALU op (no builtin on gfx950)
__device__ __forceinline__ unsigned cvtpk_bf16(float a, float b) {
  unsigned r;
  asm("v_cvt_pk_bf16_f32 %0, %1, %2" : "=v"(r) : "v"(a), "v"(b));
  return r;  // low16 = bf16(a), high16 = bf16(b)
}

// prep: [b,p][ci][co] f32 -> fragment-blocked bf16, slice-major [b][ch][p][kc]:
//   slice = (ch*9+p)*2+kc (4096 shorts each); within: f*512 + lane*8 + e
//   holds kin[b,p][ci = ch*64+kc*32+(lane>>4)*8+e][co = (f>>2)*64+(f&3)*16+(lane&15)]
__global__ void prep_kt(const float* __restrict__ kin, unsigned short* __restrict__ ktr) {
  __shared__ unsigned short t[CI * CO];  // 32 KB
  int bp = blockIdx.x;  // b*9+p, 0..287
  int b = bp / 9, p = bp % 9;
  const float* src = kin + (size_t)bp * (CI * CO);
  unsigned short* dstb = ktr + (size_t)b * (9 * CI * CO);
  for (int i = threadIdx.x; i < CI * CO / 4; i += blockDim.x) {
    f32x4 v = *(const f32x4*)(src + i * 4);
    u16x4 o;
    o.x = f2bf(v.x); o.y = f2bf(v.y); o.z = f2bf(v.z); o.w = f2bf(v.w);
    *(u16x4*)&t[i * 4] = o;
  }
  __syncthreads();
  for (int j = threadIdx.x; j < 2048; j += blockDim.x) {  // j = (sl*8+f)*64+lane
    int lane = j & 63, f = (j >> 6) & 7, sl = j >> 9;     // sl = ch*2+kc
    int ch = sl >> 1, kc = sl & 1;
    int co = (f >> 2) * 64 + (f & 3) * 16 + (lane & 15);
    int ci0 = ch * 64 + kc * 32 + (lane >> 4) * 8;
    bf16x8 v;
#pragma unroll
    for (int e = 0; e < 8; ++e) v[e] = t[(ci0 + e) * CO + co];
    int slice = (ch * 9 + p) * 2 + kc;
    *(bf16x8*)&dstb[(size_t)slice * 4096 + f * 512 + lane * 8] = v;
  }
}

// naive fallback (only if ws_size too small — not expected on this harness)
__global__ void conv_naive(const float* __restrict__ X, const float* __restrict__ Kf,
                           float* __restrict__ out) {
  int idx = blockIdx.x * blockDim.x + threadIdx.x;           // over B*HO*WO*CO
  if (idx >= NB * HO * WO * CO) return;
  int co = idx & 127, t = idx >> 7;
  int wp = t % WO; t /= WO;
  int hp = t % HO; int b = t / HO;
  const float* xb = X + (size_t)b * HH * WW * CI;
  const float* kb = Kf + (size_t)b * 9 * CI * CO;
  float s = 0.f;
  for (int p = 0; p < 9; ++p) {
    int kh = p / 3, kw = p % 3;
    const float* xr = xb + ((size_t)(hp + kh) * WW + (wp + kw)) * CI;
    const float* kr = kb + (size_t)p * CI * CO + co;
    for (int ci = 0; ci < CI; ++ci) s += xr[ci] * kr[(size_t)ci * CO];
  }
  out[idx] = s;
}

// Persistent m201-style geometry: grid 256 = 1 block/CU (93 KB LDS forces it),
// 512 thr = 2 waves/SIMD, __launch_bounds__(512,2) -> 256 regs/thread. The
// register headroom funds what 4-waves/SIMD could never hold (R1/R5/R10
// spills): acc 64 + af-dbuf 32 + Hf-dbuf 32 + 24 stage-in-flight. Each block
// owns one batch column (fixed wt), sweeps 8 tiles x 2 ci-halves = 16
// half-passes; the NEXT half-pass's A-stage streams into the other LDS
// buffer DURING the current 18 MFMA clusters (issue@s0, cvt+write@s3/s8).
__global__ __launch_bounds__(512, 2) void conv_main(
    const float* __restrict__ X, const unsigned short* __restrict__ Kt,
    float* __restrict__ out) {
  __shared__ unsigned short lds_a[2][NROW * RSTR];  // 2 x 46656 B = 93312 B

  const int tid = threadIdx.x;
  const int lane = tid & 63;
  const int wid = tid >> 6;            // 8 waves, 4 (h) x 2 (co)
  const int wr = wid >> 1, wc = wid & 1;
  const int ks = lane >> 4, lr = lane & 15;

  // block -> (xcd, batch, column): b fixed, wt fixed, ht swept 0..7
  const int bx = blockIdx.x;           // 0..255
  const int xcd = bx & 7, v = bx >> 3; // v: 0..31
  const int b = xcd * 4 + (v >> 3);    // 4 batches per XCD (L2-resident B)
  const int wt = v & 7;
  const int w0 = wt * TW;

  const float* xb = X + (size_t)b * HH * WW * CI;

  // ---- stage constants: granule i (i=0..5) = 8 ci, one b128 LDS write ----
  // slot s = tid + 512*i; row = s>>3 = (tid>>3)+64i; ci8 = tid&7.
  // b128 writes at pad-144: bank-group (9*row + ci8) mod 8 bijective per row
  // -> conflict-free (R4's 9.4M conflicts were the b64 write path).
  const int ci8 = tid & 7;
  unsigned okw = 0;
  int hI[6]; unsigned baseI[6];
#pragma unroll
  for (int i = 0; i < 6; ++i) {
    int row = (tid >> 3) + 64 * i;
    int h = row / PWw, w = row - PWw * h;
    int gw = w0 + w;
    if (gw < WW) okw |= (1u << i);
    hI[i] = h;
    baseI[i] = (unsigned)((h * WW + (gw & 127)) * CI + ci8 * 8);  // f32 elems, h0=0,ch=0
  }
  const int dst0 = (tid >> 3) * RSTR + ci8 * 8;   // shorts; granule i adds i*4608

  auto sIssue = [&](int i, int h0n, int chn, f32x4& ga, f32x4& gb) {
    bool live = (i < 5) | (tid < 32);
    bool ok = live && ((okw >> i) & 1) && (h0n + hI[i] < HH);
    const float* sp = xb + (ok ? baseI[i] + (unsigned)(h0n << 14) + (unsigned)(chn << 6)
                               : (unsigned)(ci8 << 3));
    ga = *(const f32x4*)sp;
    gb = *(const f32x4*)(sp + 4);
  };
  auto sWrite = [&](int i, int h0n, unsigned short* wbuf, const f32x4& ga, const f32x4& gb) {
    bool live = (i < 5) | (tid < 32);
    if (!live) return;                 // exec-masked; prevents row>=324 overflow
    bool ok = ((okw >> i) & 1) && (h0n + hI[i] < HH);
    u32x4 o;
    o.x = ok ? cvtpk_bf16(ga.x, ga.y) : 0u;
    o.y = ok ? cvtpk_bf16(ga.z, ga.w) : 0u;
    o.z = ok ? cvtpk_bf16(gb.x, gb.y) : 0u;
    o.w = ok ? cvtpk_bf16(gb.z, gb.w) : 0u;
    *(u32x4*)&wbuf[dst0 + i * 4608] = o;
  };

  // ---- compute: af byte = aoff + ((m+kh)*18 + kw)*144 + kc*64 (imm) ----
  const int aoff = ((wr * 4) * PWw + lr) * RSTRB + ks * 16;

  // B slices: slice = ch*18 + s; 4 contiguous 1KB bursts per wave (L2-res).
  const unsigned short* ktw = Kt + (size_t)b * 9 * CI * CO + (wc * 4) * 512 + lane * 8;
  bf16x8 HfA[4], HfB[4], afA[4], afB[4];
  auto loadB = [&](bf16x8 (&dst)[4], const unsigned short* p) {
#pragma unroll
    for (int n = 0; n < 4; ++n)
      dst[n] = *(const bf16x8*)(p + n * 512);
  };
  auto issueAf = [&](bf16x8 (&dst)[4], int s, const char* rb) {
    const int kh = s / 6, jj = s % 6;
    const int kw = jj >> 1, kc = jj & 1;
#pragma unroll
    for (int m = 0; m < 4; ++m)
      dst[m] = *(const bf16x8*)(rb + aoff +
                                ((m + kh) * PWw * RSTRB + kw * RSTRB + kc * 64));
  };

  f32x4 zero = {0.f, 0.f, 0.f, 0.f};
  f32x4 acc[4][4];
#pragma unroll
  for (int m = 0; m < 4; ++m)
#pragma unroll
    for (int n = 0; n < 4; ++n) acc[m][n] = zero;
  auto mma = [&](bf16x8 (&a)[4], bf16x8 (&h)[4]) {
    __builtin_amdgcn_s_setprio(1);
#pragma unroll
    for (int m = 0; m < 4; ++m)
#pragma unroll
      for (int n = 0; n < 4; ++n)
        acc[m][n] = __builtin_amdgcn_mfma_f32_16x16x32_bf16(a[m], h[n], acc[m][n], 0, 0, 0);
    __builtin_amdgcn_s_setprio(0);
  };

  unsigned short* const A0 = &lds_a[0][0];
  unsigned short* const A1 = &lds_a[1][0];
  float* const ob = out + (size_t)b * HO * WO * CO;

  // ---- prologue: stage pass-0 (tile 0, ch 0) into A0; prefetch B(0,0) ----
  {
    f32x4 a0, b0, a1, b1, a2, b2;
    sIssue(0, 0, 0, a0, b0); sIssue(1, 0, 0, a1, b1); sIssue(2, 0, 0, a2, b2);
    sWrite(0, 0, A0, a0, b0); sWrite(1, 0, A0, a1, b1); sWrite(2, 0, A0, a2, b2);
    sIssue(3, 0, 0, a0, b0); sIssue(4, 0, 0, a1, b1); sIssue(5, 0, 0, a2, b2);
    sWrite(3, 0, A0, a0, b0); sWrite(4, 0, A0, a1, b1); sWrite(5, 0, A0, a2, b2);
  }
  loadB(HfA, ktw);
  __syncthreads();

  f32x4 g0a, g0b, g1a, g1b, g2a, g2b;   // 3 stage granules in flight (24 regs)

#pragma unroll 1
  for (int k = 0; k < 16; ++k) {       // 16 half-passes (8 tiles x 2 ci-halves)
    const int ch = k & 1;
    const int h0 = (k >> 1) * TH;
    unsigned short* rbuf = ch ? A1 : A0;   // pass0 reads A0; stage wrote other
    unsigned short* wbuf = ch ? A0 : A1;
    const unsigned short* bq = ktw + (size_t)ch * 73728;  // ch*18*4096 shorts
    const bool stg = (k < 15);
    const int chn = (k + 1) & 1;
    const int h0n = ((k + 1) >> 1) * TH;
    const char* rb = (const char*)rbuf;

    issueAf(afA, 0, rb);               // prime A-side
#pragma unroll
    for (int u = 0; u < 9; ++u) {
      {                                 // even cluster s = 2u
        const int s = 2 * u;
        if (s == 0 && stg) {            // issue next-pass granules 0..2
          sIssue(0, h0n, chn, g0a, g0b);
          sIssue(1, h0n, chn, g1a, g1b);
          sIssue(2, h0n, chn, g2a, g2b);
        }
        loadB(HfB, bq + (size_t)(s + 1) * 4096);
        issueAf(afB, s + 1, rb);
        mma(afA, HfA);
        if (s == 8 && stg) {            // write granules 3..5 (issued @s=3)
          sWrite(3, h0n, wbuf, g0a, g0b);
          sWrite(4, h0n, wbuf, g1a, g1b);
          sWrite(5, h0n, wbuf, g2a, g2b);
        }
      }
      {                                 // odd cluster s = 2u+1
        const int s = 2 * u + 1;
        if (s < 17) {
          loadB(HfA, bq + (size_t)(s + 1) * 4096);
          issueAf(afA, s + 1, rb);
        } else if (stg) {
          loadB(HfA, ktw + (size_t)chn * 73728);  // next pass slice 0
        }
        mma(afB, HfB);
        if (s == 3 && stg) {            // write 0..2, issue 3..5
          sWrite(0, h0n, wbuf, g0a, g0b);
          sWrite(1, h0n, wbuf, g1a, g1b);
          sWrite(2, h0n, wbuf, g2a, g2b);
          sIssue(3, h0n, chn, g0a, g0b);
          sIssue(4, h0n, chn, g1a, g1b);
          sIssue(5, h0n, chn, g2a, g2b);
        }
      }
    }

    if (ch) {                           // tile done: epilogue + acc reset
#pragma unroll
      for (int m = 0; m < 4; ++m) {
        int hp = h0 + wr * 4 + m;
        if (hp >= HO) continue;
#pragma unroll
        for (int r = 0; r < 4; ++r) {
          int wp = w0 + ks * 4 + r;
          if (wp >= WO) continue;
#pragma unroll
          for (int n = 0; n < 4; ++n) {
            int co = wc * 64 + n * 16 + lr;
            ob[((size_t)hp * WO + wp) * CO + co] = acc[m][n][r];
          }
        }
      }
#pragma unroll
      for (int m = 0; m < 4; ++m)
#pragma unroll
        for (int n = 0; n < 4; ++n) acc[m][n] = zero;
    }
    if (k < 15) __syncthreads();        // stage(k+1) visible; WAR on rbuf safe
  }
}

extern "C" void kernel_launch(void* const* d_in, const int* in_sizes, int n_in,
                              void* d_out, int out_size, void* d_ws, size_t ws_size,
                              hipStream_t stream) {
  const float* X = (const float*)d_in[0];
  const float* Kf = (const float*)d_in[1];
  float* out = (float*)d_out;
  size_t need = (size_t)NB * 9 * CI * CO * sizeof(unsigned short);  // 9.4 MB
  if (d_ws != nullptr && ws_size >= need) {
    unsigned short* ktr = (unsigned short*)d_ws;
    prep_kt<<<dim3(NB * 9), 256, 0, stream>>>(Kf, ktr);
    conv_main<<<dim3(256), 512, 0, stream>>>(X, ktr, out);
  } else {
    int total = NB * HO * WO * CO;
    conv_naive<<<(total + 255) / 256, 256, 0, stream>>>(X, Kf, out);
  }
}